// Round 6
// baseline (441.970 us; speedup 1.0000x reference)
//
#include <hip/hip_runtime.h>
#include <hip/hip_bf16.h>

typedef __attribute__((ext_vector_type(4))) float f32x4;
typedef __attribute__((ext_vector_type(8))) short bf16x8;

#define EDGE_GRID 1536
#define OUT_GRID  1024

// RNE f32->bf16 pack via scalar casts: compiler fuses to v_cvt_pk_bf16_f32 (m240)
__device__ __forceinline__ unsigned int packbf(float lo, float hi) {
    __hip_bfloat16 l = __float2bfloat16(lo), h = __float2bfloat16(hi);
    const unsigned short lu = *reinterpret_cast<unsigned short*>(&l);
    const unsigned short hu = *reinterpret_cast<unsigned short*>(&h);
    return (unsigned int)lu | ((unsigned int)hu << 16);
}
__device__ __forceinline__ unsigned short bf1(float f) {
    __hip_bfloat16 v = __float2bfloat16(f);
    return *reinterpret_cast<unsigned short*>(&v);
}

// ---------------------------------------------------------------------------
// mega-prep: [0,NB_U) u = bf16(x@W1[0:64]+b1); [NB_U,+NB_C) deg histogram;
//            [+NB_C,+192) W2t/Wgt transposes.  One launch.
// ---------------------------------------------------------------------------
__global__ __launch_bounds__(256) void prep_kernel(
    const float* __restrict__ x, const float* __restrict__ W1,
    const float* __restrict__ b1, const float* __restrict__ W2,
    const float* __restrict__ Wg, const int* __restrict__ ei,
    unsigned short* __restrict__ u, unsigned short* __restrict__ W2t,
    unsigned short* __restrict__ Wgt, int* __restrict__ deg,
    int N, int E, int nTot, int NB_U, int NB_C)
{
    __shared__ float sx[8][64];
    const int blk = blockIdx.x;
    const int t = threadIdx.x;
    if (blk < NB_U) {
        const int base = blk * 8;
        for (int i = t; i < 512; i += 256) {
            const int node = base + (i >> 6);
            sx[i >> 6][i & 63] = (node < N) ? x[(size_t)node * 64 + (i & 63)] : 0.0f;
        }
        __syncthreads();
        const int half = t >> 7, col = t & 127;
        const float bias = b1[col];
        float acc[4] = {bias, bias, bias, bias};
#pragma unroll 8
        for (int k = 0; k < 64; ++k) {
            const float w = W1[k * 128 + col];
#pragma unroll
            for (int j = 0; j < 4; ++j)
                acc[j] = fmaf(sx[half * 4 + j][k], w, acc[j]);
        }
#pragma unroll
        for (int j = 0; j < 4; ++j) {
            const int node = base + half * 4 + j;
            if (node < N) u[(size_t)node * 128 + col] = bf1(acc[j]);
        }
    } else if (blk < NB_U + NB_C) {
        const int i = (blk - NB_U) * 256 + t;
        if (i < nTot) {
            const int row = (i < E) ? ei[i] : i - E;
            atomicAdd(deg + row, 1);
        }
    } else {
        const int i = (blk - NB_U - NB_C) * 256 + t;
        if (i < 16384) {
            const int n = i >> 7, k = i & 127;
            W2t[i] = bf1(W2[k * 128 + n]);
        } else if (i < 49152) {
            const int j = i - 16384;
            const int n = j >> 7, k = j & 127;
            Wgt[j] = bf1(Wg[k * 256 + n]);
        }
    }
}

// ---------------------------------------------------------------------------
// Single-block exclusive scan of deg[N] -> offs[N].  1024 thr x 52 elems.
// ---------------------------------------------------------------------------
__global__ __launch_bounds__(1024) void scan_kernel(
    const int* __restrict__ deg, int* __restrict__ offs, int N)
{
    __shared__ int sc[1024];
    const int t = threadIdx.x;
    const int c0 = t * 52;
    int v[52];
    int s = 0;
#pragma unroll
    for (int j4 = 0; j4 < 13; ++j4) {
        const int idx = c0 + j4 * 4;
        int4 d = {0, 0, 0, 0};
        if (idx + 3 < N) d = *(const int4*)(deg + idx);
        else {
            if (idx     < N) d.x = deg[idx];
            if (idx + 1 < N) d.y = deg[idx + 1];
            if (idx + 2 < N) d.z = deg[idx + 2];
        }
        v[j4*4+0] = s; s += d.x;
        v[j4*4+1] = s; s += d.y;
        v[j4*4+2] = s; s += d.z;
        v[j4*4+3] = s; s += d.w;
    }
    sc[t] = s;
    __syncthreads();
    for (int off = 1; off < 1024; off <<= 1) {
        const int val = (t >= off) ? sc[t - off] : 0;
        __syncthreads();
        sc[t] += val;
        __syncthreads();
    }
    const int base = sc[t] - s;
#pragma unroll
    for (int j4 = 0; j4 < 13; ++j4) {
        const int idx = c0 + j4 * 4;
        const int4 o = {base + v[j4*4], base + v[j4*4+1], base + v[j4*4+2], base + v[j4*4+3]};
        if (idx + 3 < N) *(int4*)(offs + idx) = o;
        else {
            if (idx     < N) offs[idx]     = o.x;
            if (idx + 1 < N) offs[idx + 1] = o.y;
            if (idx + 2 < N) offs[idx + 2] = o.z;
        }
    }
}

// ---------------------------------------------------------------------------
// scatter: deg doubles as cursor via atomicSub (within-segment order free).
// ---------------------------------------------------------------------------
__global__ void scatter_kernel(const int* __restrict__ ei, const int* __restrict__ offs,
                               int* __restrict__ deg, int* __restrict__ srow,
                               int* __restrict__ scol, int E, int nTot)
{
    const int i = blockIdx.x * 256 + threadIdx.x;
    if (i < nTot) {
        int row, col;
        if (i < E) { row = ei[i]; col = ei[E + i]; }
        else       { row = col = i - E; }
        const int p = atomicSub(deg + row, 1) - 1;
        const int q = offs[row] + p;
        srow[q] = row;
        scol[q] = col;
    }
}

// ---------------------------------------------------------------------------
// Fused edge MLP (bf16 MFMA) + segmented scatter-max, software-pipelined.
// Single sh1 buffer (phase order makes dbuf unnecessary): 26.7 KB -> 6 blk/CU.
// sW1p swizzled (+2*(k>>4)): reads hit 8 distinct banks instead of 2.
// ---------------------------------------------------------------------------
__global__ __launch_bounds__(256, 6) void edge_kernel(
    const unsigned short* __restrict__ u, const float* __restrict__ pos,
    const float* __restrict__ W1, const float* __restrict__ b2,
    const unsigned short* __restrict__ W2t, const int* __restrict__ srow,
    const int* __restrict__ scol, unsigned int* __restrict__ agg,
    int nTot, int nTiles)
{
    __shared__ unsigned short sh1[4096];     // [32 e][128 k] bf16, granule^=(e&7)
    __shared__ float          sh2[4096];     // [32 e][128 n] f32, col=(n+e*4)&127
    __shared__ float          sW1p[480];     // [3][160] swizzled: r*160 + k + 2*(k>>4)
    __shared__ int            sRowL[2][32];

    const int t = threadIdx.x;
    const int wv = t >> 6, lane = t & 63;
    const int m = lane & 15, g = lane >> 4;
    const int n0 = wv * 32 + m;
    const int e_h1 = t >> 3, s8 = t & 7, kc = s8 * 16;
    const int wb = s8 * 18;                       // swizzled sW1p base
    const int cR = t & 127, hR = t >> 7;

    // W2 B-fragments -> registers (16 VGPRs), bias -> registers
    bf16x8 bfr[2][4];
#pragma unroll
    for (int nb = 0; nb < 2; ++nb)
#pragma unroll
        for (int ks = 0; ks < 4; ++ks)
            bfr[nb][ks] = *(const bf16x8*)(W2t + (size_t)(n0 + nb * 16) * 128 + (ks * 4 + g) * 8);
    const float bia0 = b2[n0], bia1 = b2[n0 + 16];

    for (int i = t; i < 384; i += 256) {
        const int r = i >> 7, k = i & 127;
        sW1p[r * 160 + k + 2 * (k >> 4)] = W1[64 * 128 + i];
    }
    __syncthreads();

    auto gather = [&](int tile, int& c, float& r0, float& r1, float& r2,
                      uint4& ua, uint4& ub, int& rowStage) {
        c = -1; rowStage = -1;
        if (tile < nTiles) {
            const int p = tile * 32 + e_h1;
            if (p < nTot) {
                c = scol[p];
                const int r = srow[p];
                r0 = pos[c * 3 + 0] - pos[r * 3 + 0];
                r1 = pos[c * 3 + 1] - pos[r * 3 + 1];
                r2 = pos[c * 3 + 2] - pos[r * 3 + 2];
                const uint4* up = (const uint4*)(u + (size_t)c * 128 + kc);
                ua = up[0]; ub = up[1];
            }
            if (t < 32) {
                const int p2 = tile * 32 + t;
                rowStage = (p2 < nTot) ? srow[p2] : -1;
            }
        }
    };
    auto computeH1 = [&](int buf, int c, float r0, float r1, float r2,
                         uint4 ua, uint4 ub, int rowStage) {
        unsigned int ow[8] = {0,0,0,0,0,0,0,0};
        if (c >= 0) {
            const unsigned int uw[8] = {ua.x, ua.y, ua.z, ua.w, ub.x, ub.y, ub.z, ub.w};
#pragma unroll
            for (int j = 0; j < 8; ++j) {
                const int wk = wb + 2 * j;
                float lo = __uint_as_float(uw[j] << 16);
                float hi = __uint_as_float(uw[j] & 0xFFFF0000u);
                lo = fmaf(r0, sW1p[wk],       fmaf(r1, sW1p[160 + wk],     fmaf(r2, sW1p[320 + wk],     lo)));
                hi = fmaf(r0, sW1p[wk + 1],   fmaf(r1, sW1p[160 + wk + 1], fmaf(r2, sW1p[320 + wk + 1], hi)));
                ow[j] = packbf(fmaxf(lo, 0.0f), fmaxf(hi, 0.0f));
            }
        }
        const int g0 = e_h1 * 16 + s8 * 2;
        ((int4*)sh1)[(g0)     ^ (e_h1 & 7)] = make_int4(ow[0], ow[1], ow[2], ow[3]);
        ((int4*)sh1)[(g0 + 1) ^ (e_h1 & 7)] = make_int4(ow[4], ow[5], ow[6], ow[7]);
        if (t < 32) sRowL[buf][t] = rowStage;
    };

    // prologue: tile = blockIdx.x into sh1 / sRowL[0]
    {
        int c, rs; float r0 = 0, r1 = 0, r2 = 0; uint4 ua = {0,0,0,0}, ub = {0,0,0,0};
        gather(blockIdx.x, c, r0, r1, r2, ua, ub, rs);
        computeH1(0, c, r0, r1, r2, ua, ub, rs);
    }
    __syncthreads();

    int b = 0;
    for (int tile = blockIdx.x; tile < nTiles; tile += EDGE_GRID, b ^= 1) {
        const int nextTile = tile + EDGE_GRID;

        // ---- A: issue next tile's gathers (latency hidden under B)
        int c, rs; float r0 = 0, r1 = 0, r2 = 0; uint4 ua = {0,0,0,0}, ub = {0,0,0,0};
        gather(nextTile, c, r0, r1, r2, ua, ub, rs);

        // ---- B: h2 = relu(h1 @ W2 + b2) via MFMA (B-operand in regs) -> sh2
        {
            f32x4 acc0 = {0,0,0,0}, acc1 = {0,0,0,0}, acc2 = {0,0,0,0}, acc3 = {0,0,0,0};
#pragma unroll
            for (int ks = 0; ks < 4; ++ks) {
                const int slot = ks * 4 + g;
                const bf16x8 a0 = *(const bf16x8*)&sh1[(m        * 16 + (slot ^ (m & 7))) << 3];
                const bf16x8 a1 = *(const bf16x8*)&sh1[((m + 16) * 16 + (slot ^ (m & 7))) << 3];
                acc0 = __builtin_amdgcn_mfma_f32_16x16x32_bf16(a0, bfr[0][ks], acc0, 0, 0, 0);
                acc1 = __builtin_amdgcn_mfma_f32_16x16x32_bf16(a0, bfr[1][ks], acc1, 0, 0, 0);
                acc2 = __builtin_amdgcn_mfma_f32_16x16x32_bf16(a1, bfr[0][ks], acc2, 0, 0, 0);
                acc3 = __builtin_amdgcn_mfma_f32_16x16x32_bf16(a1, bfr[1][ks], acc3, 0, 0, 0);
            }
#pragma unroll
            for (int rg = 0; rg < 4; ++rg) {
                const int e0 = g * 4 + rg, e1 = 16 + g * 4 + rg;
                sh2[e0 * 128 + ((n0      + e0 * 4) & 127)] = fmaxf(acc0[rg] + bia0, 0.0f);
                sh2[e0 * 128 + ((n0 + 16 + e0 * 4) & 127)] = fmaxf(acc1[rg] + bia1, 0.0f);
                sh2[e1 * 128 + ((n0      + e1 * 4) & 127)] = fmaxf(acc2[rg] + bia0, 0.0f);
                sh2[e1 * 128 + ((n0 + 16 + e1 * 4) & 127)] = fmaxf(acc3[rg] + bia1, 0.0f);
            }
        }
        __syncthreads();
        // after this barrier every wave is done reading sh1 (B) and sh2 is
        // fully written -> D may overwrite sh1 while C reads sh2.

        // ---- D: next tile's h1 from gathered regs -> sh1 / sRowL[b^1]
        if (nextTile < nTiles)
            computeH1(b ^ 1, c, r0, r1, r2, ua, ub, rs);

        // ---- C: segmented max over sorted rows + guarded atomicMax
        {
            float run = 0.0f; int cur = -1;
            const int ebase = hR * 16;
            for (int i = 0; i < 16; ++i) {
                const int e = ebase + i;
                const int r = sRowL[b][e];
                if (r < 0) break;
                const float v = sh2[e * 128 + ((cR + e * 4) & 127)];
                if (r != cur) {
                    if (cur >= 0) {
                        const unsigned int bits = __float_as_uint(run);
                        unsigned int* dst = agg + (size_t)cur * 128 + cR;
                        if (bits > *dst) atomicMax(dst, bits);
                    }
                    cur = r; run = v;
                } else run = fmaxf(run, v);
            }
            if (cur >= 0) {
                const unsigned int bits = __float_as_uint(run);
                unsigned int* dst = agg + (size_t)cur * 128 + cR;
                if (bits > *dst) atomicMax(dst, bits);
            }
        }
        __syncthreads();
    }
}

// ---------------------------------------------------------------------------
// out = relu(agg @ Wg + bg) via bf16 MFMA; Wg fragments in registers.
// LDS = 8 KB staging only.  Tile = 32 nodes x 256 cols.
// ---------------------------------------------------------------------------
__global__ __launch_bounds__(256, 4) void out_kernel(
    const float* __restrict__ agg, const unsigned short* __restrict__ Wgt,
    const float* __restrict__ bg, float* __restrict__ out, int N, int nTiles)
{
    __shared__ unsigned short sA[4096];   // [32 e][128 k] bf16, granule^=(e&7)

    const int t = threadIdx.x;
    const int wv = t >> 6, lane = t & 63;
    const int m = lane & 15, g = lane >> 4;
    const int eA = t >> 3, kcA = (t & 7) * 16;

    // Wg B-fragments -> registers (64 VGPRs): wave wv owns cols wv*64..+63
    bf16x8 wfr[4][4];
    float bgv[4];
#pragma unroll
    for (int nt = 0; nt < 4; ++nt) {
        const int n = wv * 64 + nt * 16 + m;
#pragma unroll
        for (int ks = 0; ks < 4; ++ks)
            wfr[nt][ks] = *(const bf16x8*)(Wgt + (size_t)n * 128 + (ks * 4 + g) * 8);
        bgv[nt] = bg[n];
    }

    for (int tile = blockIdx.x; tile < nTiles; tile += OUT_GRID) {
        const int tbase = tile * 32;

        // stage A: bf16(agg rows)
        {
            unsigned int ow[8] = {0,0,0,0,0,0,0,0};
            const int node = tbase + eA;
            if (node < N) {
                const float4* ap = (const float4*)(agg + (size_t)node * 128 + kcA);
#pragma unroll
                for (int j = 0; j < 4; ++j) {
                    const float4 v = ap[j];
                    ow[j * 2 + 0] = packbf(v.x, v.y);
                    ow[j * 2 + 1] = packbf(v.z, v.w);
                }
            }
            const int g0 = eA * 16 + (t & 7) * 2;
            ((int4*)sA)[(g0)     ^ (eA & 7)] = make_int4(ow[0], ow[1], ow[2], ow[3]);
            ((int4*)sA)[(g0 + 1) ^ (eA & 7)] = make_int4(ow[4], ow[5], ow[6], ow[7]);
        }
        __syncthreads();

        f32x4 acc[2][4] = {{{0,0,0,0},{0,0,0,0},{0,0,0,0},{0,0,0,0}},
                           {{0,0,0,0},{0,0,0,0},{0,0,0,0},{0,0,0,0}}};
#pragma unroll
        for (int ks = 0; ks < 4; ++ks) {
            const int slot = ks * 4 + g;
            const bf16x8 a0 = *(const bf16x8*)&sA[(m        * 16 + (slot ^ (m & 7))) << 3];
            const bf16x8 a1 = *(const bf16x8*)&sA[((m + 16) * 16 + (slot ^ (m & 7))) << 3];
#pragma unroll
            for (int nt = 0; nt < 4; ++nt) {
                acc[0][nt] = __builtin_amdgcn_mfma_f32_16x16x32_bf16(a0, wfr[nt][ks], acc[0][nt], 0, 0, 0);
                acc[1][nt] = __builtin_amdgcn_mfma_f32_16x16x32_bf16(a1, wfr[nt][ks], acc[1][nt], 0, 0, 0);
            }
        }
#pragma unroll
        for (int mg = 0; mg < 2; ++mg)
#pragma unroll
        for (int nt = 0; nt < 4; ++nt) {
            const int n = wv * 64 + nt * 16 + m;
#pragma unroll
            for (int rg = 0; rg < 4; ++rg) {
                const int node = tbase + mg * 16 + g * 4 + rg;
                if (node < N)
                    out[(size_t)node * 256 + n] = fmaxf(acc[mg][nt][rg] + bgv[nt], 0.0f);
            }
        }
        __syncthreads();
    }
}

// ---------------------------------------------------------------------------
extern "C" void kernel_launch(void* const* d_in, const int* in_sizes, int n_in,
                              void* d_out, int out_size, void* d_ws, size_t ws_size,
                              hipStream_t stream)
{
    const float* x   = (const float*)d_in[0];
    const float* pos = (const float*)d_in[1];
    const float* W1  = (const float*)d_in[2];
    const float* b1  = (const float*)d_in[3];
    const float* W2  = (const float*)d_in[4];
    const float* b2  = (const float*)d_in[5];
    const float* Wg  = (const float*)d_in[6];
    const float* bg  = (const float*)d_in[7];
    const int*   ei  = (const int*)d_in[8];
    float* out = (float*)d_out;

    const int N    = in_sizes[1] / 3;
    const int E    = in_sizes[8] / 2;
    const int nTot = E + N;

    size_t off = 0;
    auto alloc = [&](size_t bytes) -> void* {
        void* p = (char*)d_ws + off;
        off += (bytes + 255) & ~(size_t)255;
        return p;
    };
    unsigned short* u    = (unsigned short*)alloc((size_t)N * 128 * 2);
    unsigned int*   agg  = (unsigned int*)  alloc((size_t)N * 128 * 4);
    int*            deg  = (int*)           alloc((size_t)N * 4);
    int*            offs = (int*)           alloc((size_t)N * 4);
    int*            srow = (int*)           alloc((size_t)nTot * 4);
    int*            scol = (int*)           alloc((size_t)nTot * 4);
    unsigned short* W2t  = (unsigned short*)alloc(16384 * 2);
    unsigned short* Wgt  = (unsigned short*)alloc(32768 * 2);

    hipMemsetAsync(agg, 0, (size_t)N * 128 * 4, stream);
    hipMemsetAsync(deg, 0, (size_t)N * 4, stream);

    const int NB_U = (N + 7) / 8;
    const int NB_C = (nTot + 255) / 256;
    const int NB_T = 192;
    hipLaunchKernelGGL(prep_kernel, dim3(NB_U + NB_C + NB_T), dim3(256), 0, stream,
                       x, W1, b1, W2, Wg, ei, u, W2t, Wgt, deg, N, E, nTot, NB_U, NB_C);

    hipLaunchKernelGGL(scan_kernel, dim3(1), dim3(1024), 0, stream, deg, offs, N);

    hipLaunchKernelGGL(scatter_kernel, dim3((nTot + 255) / 256), dim3(256), 0, stream,
                       ei, offs, deg, srow, scol, E, nTot);

    const int nTilesE = (nTot + 31) / 32;
    hipLaunchKernelGGL(edge_kernel, dim3(EDGE_GRID), dim3(256), 0, stream,
                       u, pos, W1, b2, W2t, srow, scol, agg, nTot, nTilesE);

    const int nTilesO = (N + 31) / 32;
    hipLaunchKernelGGL(out_kernel, dim3(OUT_GRID), dim3(256), 0, stream,
                       (const float*)agg, Wgt, bg, out, N, nTilesO);
}